// Round 4
// baseline (345.782 us; speedup 1.0000x reference)
//
#include <hip/hip_runtime.h>
#include <hip/hip_bf16.h>
#include <math.h>

// Transformer layer: B=2 S=2048 D=1024 H=16 HD=64 FF=4096, fp32 I/O.
// Heavy GEMMs in bf16 MFMA (256x256 4-phase/tile, depth-5-half pipeline).

#define BB 2
#define SS 2048
#define DD 1024
#define HH 16
#define HDIM 64
#define FFD 4096
#define NTOK (BB*SS)
#define LOG2E 1.4426950408889634f

typedef __attribute__((ext_vector_type(8))) short bf16x8;
typedef __attribute__((ext_vector_type(4))) float f32x4;
typedef __attribute__((ext_vector_type(16))) float f32x16;
typedef __attribute__((ext_vector_type(4))) unsigned int u32x4;

#if __has_builtin(__builtin_amdgcn_exp2f)
#define EXP2(x) __builtin_amdgcn_exp2f(x)
#else
#define EXP2(x) exp2f(x)
#endif

#define BAR __builtin_amdgcn_s_barrier
#define SCB __builtin_amdgcn_sched_barrier
#define VM6 asm volatile("s_waitcnt vmcnt(6)" ::: "memory")
#define VM4 asm volatile("s_waitcnt vmcnt(4)" ::: "memory")
#define VM2 asm volatile("s_waitcnt vmcnt(2)" ::: "memory")
#define VM0 asm volatile("s_waitcnt vmcnt(0)" ::: "memory")
#define LGK0 asm volatile("s_waitcnt lgkmcnt(0)" ::: "memory")

__device__ __forceinline__ void gl_lds16(const void* g, void* l) {
  __builtin_amdgcn_global_load_lds(
      (const __attribute__((address_space(1))) unsigned int*)g,
      (__attribute__((address_space(3))) unsigned int*)l, 16, 0, 0);
}

__device__ __forceinline__ short f2bf(float f) {
  unsigned int u = __builtin_bit_cast(unsigned int, f);
  unsigned int r = (u + 0x7fffu + ((u >> 16) & 1u)) >> 16;
  return (short)r;
}
__device__ __forceinline__ unsigned pk2(float lo, float hi) {
  return (unsigned)(unsigned short)f2bf(lo) | ((unsigned)(unsigned short)f2bf(hi) << 16);
}

// ---------------- transpose + fp32->bf16 convert: wt[n][k] = bf16(w[k][n]) ----
__global__ __launch_bounds__(256) void convT(const float* __restrict__ w,
                                             __hip_bfloat16* __restrict__ wt,
                                             int K, int N) {
  __shared__ float tile[32][33];
  int k0 = blockIdx.y * 32, n0 = blockIdx.x * 32;
  int tx = threadIdx.x & 31, ty = threadIdx.x >> 5;
#pragma unroll
  for (int i = 0; i < 4; ++i) {
    int r = ty + i * 8;
    tile[r][tx] = w[(size_t)(k0 + r) * N + n0 + tx];
  }
  __syncthreads();
#pragma unroll
  for (int i = 0; i < 4; ++i) {
    int r = ty + i * 8;
    wt[(size_t)(n0 + r) * K + k0 + tx] = __float2bfloat16(tile[tx][r]);
  }
}

// ---------------- LayerNorm (fp32 in -> bf16 out), one wave per row ----------
__global__ __launch_bounds__(256) void ln_bf16(const float* __restrict__ x,
                                               const float* __restrict__ g,
                                               const float* __restrict__ be,
                                               __hip_bfloat16* __restrict__ out) {
  int w = threadIdx.x >> 6, lane = threadIdx.x & 63;
  int row = blockIdx.x * 4 + w;
  const float* xr = x + (size_t)row * DD;
  float4 v[4];
  float sum = 0.f, sq = 0.f;
#pragma unroll
  for (int i = 0; i < 4; ++i) {
    v[i] = *(const float4*)(xr + lane * 4 + i * 256);
    sum += v[i].x + v[i].y + v[i].z + v[i].w;
    sq += v[i].x * v[i].x + v[i].y * v[i].y + v[i].z * v[i].z + v[i].w * v[i].w;
  }
#pragma unroll
  for (int off = 1; off < 64; off <<= 1) {
    sum += __shfl_xor(sum, off);
    sq += __shfl_xor(sq, off);
  }
  float mu = sum * (1.f / 1024.f);
  float var = sq * (1.f / 1024.f) - mu * mu;
  float rs = rsqrtf(var + 1e-12f);
  __hip_bfloat16* orow = out + (size_t)row * DD;
#pragma unroll
  for (int i = 0; i < 4; ++i) {
    int c = lane * 4 + i * 256;
    float4 gg = *(const float4*)(g + c);
    float4 bb = *(const float4*)(be + c);
    short4 o;
    o.x = f2bf((v[i].x - mu) * rs * gg.x + bb.x);
    o.y = f2bf((v[i].y - mu) * rs * gg.y + bb.y);
    o.z = f2bf((v[i].z - mu) * rs * gg.z + bb.z);
    o.w = f2bf((v[i].w - mu) * rs * gg.w + bb.w);
    *(short4*)((short*)orow + c) = o;
  }
}

// ================= 256x256 GEMM, depth-5-half pipeline ======================
// C[M,N] = A[M,K] * BT[N,K]^T.  8 waves; 4 quadrant-phases per K-tile (BK=64).
// Half-tile order per tile: [A0, B0, B1, A1]; phase p stages half H(p+5);
// post-MFMA counted vmcnt(6) drains through H(p+2) (next phase's ds_reads).
// EPI 1: +bias, gelu -> bf16 (bounce)        [FF1]
// EPI 4: raw -> bf16 partial (bounce)        [FF2 split-K, offsets 0/8/24MB]
// EPI 5: QKV fused: Q,K +bias -> bf16; V +bias -> bf16 transposed
// EPI 6: raw -> bf16 partial (bounce)        [O-proj split-K, offsets 24+8z MB]

__device__ __forceinline__ void stageH(int h, int NT4,
    const __hip_bfloat16* __restrict__ A, const __hip_bfloat16* __restrict__ BT,
    int m0, int n0, int K, int kt0, char* lds, int tid, int srow, int scol) {
  if (h >= NT4) return;
  int tl = h >> 2, hf = h & 3;
  // LDS regions within 64KB buffer: A0@0, A1@16384, B0@32768, B1@49152
  int reg = (hf == 0) ? 0 : (hf == 1) ? 32768 : (hf == 2) ? 49152 : 16384;
  char* dst = lds + (tl & 1) * 65536 + reg + tid * 16;
  const bool isA = (hf == 0 || hf == 3);
  const __hip_bfloat16* src = isA ? A : BT;
  int rb = (isA ? m0 : n0) + ((hf == 2 || hf == 3) ? 128 : 0) + srow;
  size_t g = (size_t)rb * K + (size_t)(kt0 + tl) * 64 + scol;
  gl_lds16(src + g, dst);
  gl_lds16(src + g + (size_t)64 * K, dst + 8192);
}

template <int QM>
__device__ __forceinline__ void rdA(bf16x8 (&af)[4][2], const char* buf,
                                    int wm64, int row16, int grp) {
#pragma unroll
  for (int mf = 0; mf < 4; ++mf) {
    int rh = wm64 + mf * 16 + row16;
    const char* rp = buf + QM * 16384 + rh * 128;
    int x7 = rh & 7;
#pragma unroll
    for (int kc = 0; kc < 2; ++kc)
      af[mf][kc] = *(const bf16x8*)(rp + (((kc * 4 + grp) ^ x7) << 4));
  }
}
template <int QN>
__device__ __forceinline__ void rdB(bf16x8 (&bfr)[2][2], const char* buf,
                                    int wn32, int row16, int grp) {
#pragma unroll
  for (int nf = 0; nf < 2; ++nf) {
    int rh = wn32 + nf * 16 + row16;
    const char* rp = buf + 32768 + QN * 16384 + rh * 128;
    int x7 = rh & 7;
#pragma unroll
    for (int kc = 0; kc < 2; ++kc)
      bfr[nf][kc] = *(const bf16x8*)(rp + (((kc * 4 + grp) ^ x7) << 4));
  }
}
template <int QM, int QN>
__device__ __forceinline__ void mmStep(f32x4 (&acc)[2][4][2][2],
                                       const bf16x8 (&af)[4][2],
                                       const bf16x8 (&bfr)[2][2]) {
#pragma unroll
  for (int mf = 0; mf < 4; ++mf)
#pragma unroll
    for (int nf = 0; nf < 2; ++nf) {
      acc[QM][mf][QN][nf] = __builtin_amdgcn_mfma_f32_16x16x32_bf16(
          af[mf][0], bfr[nf][0], acc[QM][mf][QN][nf], 0, 0, 0);
      acc[QM][mf][QN][nf] = __builtin_amdgcn_mfma_f32_16x16x32_bf16(
          af[mf][1], bfr[nf][1], acc[QM][mf][QN][nf], 0, 0, 0);
    }
}

template <int EPI>
__global__ __launch_bounds__(512, 2) void gemm256(
    const __hip_bfloat16* __restrict__ A, const __hip_bfloat16* __restrict__ BT,
    const float* __restrict__ bA, const float* __restrict__ bB,
    const float* __restrict__ bC,
    void* __restrict__ C0, void* __restrict__ C1, void* __restrict__ C2,
    int M, int N, int K, int tilesN, int kSplit) {
  __shared__ __align__(16) char lds[131072];
  const int tid = threadIdx.x, lane = tid & 63, w = tid >> 6;
  const int row16 = lane & 15, grp = lane >> 4;
  const int wm64 = ((w >> 2) & 1) * 64, wn32 = (w & 3) * 32;
  const int srow = tid >> 3, scol = ((tid & 7) ^ (srow & 7)) * 8;

  const int nwg = gridDim.x, bid = blockIdx.x;
  const int swz = (bid & 7) * (nwg >> 3) + (bid >> 3);
  const int tm = swz / tilesN, tn = swz - tm * tilesN;
  const int m0 = tm * 256, n0 = tn * 256;
  const int NTtot = K >> 6;
  const int z = blockIdx.y;
  const int kt0 = (z * NTtot) / kSplit;
  const int NT = ((z + 1) * NTtot) / kSplit - kt0;
  const int NT4 = NT * 4;

  bf16x8 af[4][2], bfr[2][2];
  f32x4 acc[2][4][2][2] = {};

  // prologue: H0..H4 (tile0 A0,B0,B1,A1 + tile1 A0); drain through H1
#pragma unroll
  for (int h = 0; h < 5; ++h)
    stageH(h, NT4, A, BT, m0, n0, K, kt0, lds, tid, srow, scol);
  VM6;
  BAR();

  for (int t = 0; t < NT; ++t) {
    const char* buf = lds + (t & 1) * 65536;
    const int p = t * 4;
    const bool sl = (t == NT - 2), la = (t == NT - 1);
    // phase 0: quadrant (0,0); stage H(p+5) = B0(t+1)
    rdA<0>(af, buf, wm64, row16, grp);
    rdB<0>(bfr, buf, wn32, row16, grp);
    stageH(p + 5, NT4, A, BT, m0, n0, K, kt0, lds, tid, srow, scol);
    BAR(); LGK0; SCB(0);
    __builtin_amdgcn_s_setprio(1);
    mmStep<0, 0>(acc, af, bfr);
    __builtin_amdgcn_s_setprio(0); SCB(0);
    if (la) { VM2; } else { VM6; }
    BAR();
    // phase 1: quadrant (0,1); stage H(p+6) = B1(t+1)
    rdB<1>(bfr, buf, wn32, row16, grp);
    stageH(p + 6, NT4, A, BT, m0, n0, K, kt0, lds, tid, srow, scol);
    BAR(); LGK0; SCB(0);
    __builtin_amdgcn_s_setprio(1);
    mmStep<0, 1>(acc, af, bfr);
    __builtin_amdgcn_s_setprio(0); SCB(0);
    if (la) { VM0; } else { VM6; }
    BAR();
    // phase 2: quadrant (1,1); stage H(p+7) = A1(t+1)
    rdA<1>(af, buf, wm64, row16, grp);
    stageH(p + 7, NT4, A, BT, m0, n0, K, kt0, lds, tid, srow, scol);
    BAR(); LGK0; SCB(0);
    __builtin_amdgcn_s_setprio(1);
    mmStep<1, 1>(acc, af, bfr);
    __builtin_amdgcn_s_setprio(0); SCB(0);
    if (!la) { VM6; }
    BAR();
    // phase 3: quadrant (1,0); stage H(p+8) = A0(t+2)
    rdB<0>(bfr, buf, wn32, row16, grp);
    stageH(p + 8, NT4, A, BT, m0, n0, K, kt0, lds, tid, srow, scol);
    BAR(); LGK0; SCB(0);
    __builtin_amdgcn_s_setprio(1);
    mmStep<1, 0>(acc, af, bfr);
    __builtin_amdgcn_s_setprio(0); SCB(0);
    if (!la) { if (sl) { VM4; } else { VM6; } }
    BAR();
  }

  // ---------------- epilogues ----------------
  if constexpr (EPI == 5) {
    if (n0 >= 2048) {  // V section: direct transposed bf16 store
      float bv_[2][2];
#pragma unroll
      for (int qn = 0; qn < 2; ++qn)
#pragma unroll
        for (int nf = 0; nf < 2; ++nf)
          bv_[qn][nf] = bC[n0 - 2048 + qn * 128 + wn32 + nf * 16 + row16];
#pragma unroll
      for (int qm = 0; qm < 2; ++qm)
#pragma unroll
        for (int mf = 0; mf < 4; ++mf)
#pragma unroll
          for (int qn = 0; qn < 2; ++qn)
#pragma unroll
            for (int nf = 0; nf < 2; ++nf) {
              int tokB = m0 + qm * 128 + wm64 + mf * 16 + grp * 4;
              int vr = ((tokB >> 11) << 10) + (n0 - 2048) + qn * 128 + wn32 + nf * 16 + row16;
              f32x4 a = acc[qm][mf][qn][nf];
              float bv = bv_[qn][nf];
              uint2 val = make_uint2(pk2(a[0] + bv, a[1] + bv), pk2(a[2] + bv, a[3] + bv));
              *(uint2*)((__hip_bfloat16*)C2 + (size_t)vr * 2048 + (tokB & 2047)) = val;
            }
      return;
    }
  }

  if constexpr (EPI == 1 || EPI == 4 || EPI == 5 || EPI == 6) {  // bf16 bounce
    __hip_bfloat16* outP = nullptr;
    int ldO = N, colB = n0;
    const float* bp = nullptr;
    if constexpr (EPI == 1) { outP = (__hip_bfloat16*)C0; bp = bA; }
    if constexpr (EPI == 4) {
      size_t off = (z == 0) ? 0ull : ((z == 1) ? (8ull << 20) : (24ull << 20));
      outP = (__hip_bfloat16*)((char*)C0 + off);
    }
    if constexpr (EPI == 6) {
      size_t off = (24ull << 20) + ((size_t)z << 23);
      outP = (__hip_bfloat16*)((char*)C0 + off);
    }
    if constexpr (EPI == 5) {
      bool k2 = n0 >= 1024;
      outP = (__hip_bfloat16*)(k2 ? C1 : C0);
      ldO = 1024; colB = n0 & 1023;
      bp = k2 ? bB : bA;
    }
    float bv_[2][2];
#pragma unroll
    for (int qn = 0; qn < 2; ++qn)
#pragma unroll
      for (int nf = 0; nf < 2; ++nf)
        bv_[qn][nf] = bp ? bp[colB + qn * 128 + wn32 + nf * 16 + row16] : 0.f;
#pragma unroll
    for (int ph = 0; ph < 2; ++ph) {
      BAR();
#pragma unroll
      for (int qm = 0; qm < 2; ++qm)
#pragma unroll
        for (int mf = 0; mf < 4; ++mf)
#pragma unroll
          for (int nf = 0; nf < 2; ++nf) {
            int mloc = qm * 128 + wm64 + mf * 16 + grp * 4;
            int nloc = wn32 + nf * 16 + row16;
            f32x4 a = acc[qm][mf][ph][nf];
#pragma unroll
            for (int r = 0; r < 4; ++r) {
              float v = a[r] + bv_[ph][nf];
              if constexpr (EPI == 1)
                v = 0.5f * v * (1.0f + erff(v * 0.70710678118654752f));
              *(short*)(lds + (mloc + r) * 272 + nloc * 2) = f2bf(v);
            }
          }
      BAR();
#pragma unroll
      for (int i = 0; i < 8; ++i) {
        int c = tid + i * 512;
        int mmr = c >> 4, nc = c & 15;
        u32x4 vv = *(const u32x4*)(lds + mmr * 272 + nc * 16);
        *(u32x4*)(outP + (size_t)(m0 + mmr) * ldO + colB + ph * 128 + nc * 8) = vv;
      }
    }
  }
}

// ---------------- FF2 split-K reduce: out = h1 + b2 + sum(3 partials) --------
__global__ __launch_bounds__(256) void reduce3(const __hip_bfloat16* __restrict__ p0,
                                               const __hip_bfloat16* __restrict__ p1,
                                               const __hip_bfloat16* __restrict__ p2,
                                               const float* __restrict__ h1,
                                               const float* __restrict__ b2,
                                               float* __restrict__ out) {
  int idx = (blockIdx.x * 256 + threadIdx.x) * 8;
  int n = idx & 1023;
  bf16x8 a = *(const bf16x8*)(p0 + idx);
  bf16x8 b = *(const bf16x8*)(p1 + idx);
  bf16x8 c = *(const bf16x8*)(p2 + idx);
  float4 hA = *(const float4*)(h1 + idx), hB = *(const float4*)(h1 + idx + 4);
  float4 bA = *(const float4*)(b2 + n), bB = *(const float4*)(b2 + n + 4);
  float o[8];
#pragma unroll
  for (int j = 0; j < 8; ++j) {
    float fa = __builtin_bit_cast(float, ((unsigned)(unsigned short)a[j]) << 16);
    float fb = __builtin_bit_cast(float, ((unsigned)(unsigned short)b[j]) << 16);
    float fc = __builtin_bit_cast(float, ((unsigned)(unsigned short)c[j]) << 16);
    o[j] = fa + fb + fc;
  }
  float4 r0 = make_float4(o[0] + hA.x + bA.x, o[1] + hA.y + bA.y,
                          o[2] + hA.z + bA.z, o[3] + hA.w + bA.w);
  float4 r1 = make_float4(o[4] + hB.x + bB.x, o[5] + hB.y + bB.y,
                          o[6] + hB.z + bB.z, o[7] + hB.w + bB.w);
  *(float4*)(out + idx) = r0;
  *(float4*)(out + idx + 4) = r1;
}

// ---------------- O-proj split-K reduce: h1 = x + bo + sum(4 partials) -------
__global__ __launch_bounds__(256) void reduce4(const __hip_bfloat16* __restrict__ p0,
                                               const __hip_bfloat16* __restrict__ p1,
                                               const __hip_bfloat16* __restrict__ p2,
                                               const __hip_bfloat16* __restrict__ p3,
                                               const float* __restrict__ x,
                                               const float* __restrict__ bo,
                                               float* __restrict__ out) {
  int idx = (blockIdx.x * 256 + threadIdx.x) * 8;
  int n = idx & 1023;
  bf16x8 a = *(const bf16x8*)(p0 + idx);
  bf16x8 b = *(const bf16x8*)(p1 + idx);
  bf16x8 c = *(const bf16x8*)(p2 + idx);
  bf16x8 d = *(const bf16x8*)(p3 + idx);
  float4 hA = *(const float4*)(x + idx), hB = *(const float4*)(x + idx + 4);
  float4 bA = *(const float4*)(bo + n), bB = *(const float4*)(bo + n + 4);
  float o[8];
#pragma unroll
  for (int j = 0; j < 8; ++j) {
    float fa = __builtin_bit_cast(float, ((unsigned)(unsigned short)a[j]) << 16);
    float fb = __builtin_bit_cast(float, ((unsigned)(unsigned short)b[j]) << 16);
    float fc = __builtin_bit_cast(float, ((unsigned)(unsigned short)c[j]) << 16);
    float fd = __builtin_bit_cast(float, ((unsigned)(unsigned short)d[j]) << 16);
    o[j] = (fa + fb) + (fc + fd);
  }
  float4 r0 = make_float4(o[0] + hA.x + bA.x, o[1] + hA.y + bA.y,
                          o[2] + hA.z + bA.z, o[3] + hA.w + bA.w);
  float4 r1 = make_float4(o[4] + hB.x + bB.x, o[5] + hB.y + bB.y,
                          o[6] + hB.z + bB.z, o[7] + hB.w + bB.w);
  *(float4*)(out + idx) = r0;
  *(float4*)(out + idx + 4) = r1;
}

// ---------------- Flash attention v2 (unchanged, verified) -------------------
__global__ __launch_bounds__(512) void flash_attn2(
    const __hip_bfloat16* __restrict__ Q,
    const __hip_bfloat16* __restrict__ Kg,
    const __hip_bfloat16* __restrict__ VTg,
    const float* __restrict__ mask,
    __hip_bfloat16* __restrict__ O) {
  __shared__ __align__(16) char lds[33280];
  const int t = threadIdx.x, lane = t & 63, w = t >> 6;
  const int l31 = lane & 31, hi = lane >> 5;
  const int q0 = blockIdx.x * 256;
  const int bh = blockIdx.y, b = bh >> 4, h = bh & 15;
  const int qrow = q0 + w * 32 + l31;

  bf16x8 qf[4];
  {
    const __hip_bfloat16* qp = Q + ((size_t)(b * SS + qrow)) * DD + h * HDIM + hi * 8;
    qf[0] = *(const bf16x8*)(qp);
    qf[1] = *(const bf16x8*)(qp + 16);
    qf[2] = *(const bf16x8*)(qp + 32);
    qf[3] = *(const bf16x8*)(qp + 48);
  }
  f32x16 ctx0 = {}, ctx1 = {};
  float m = -1e30f, l = 0.f, mC = -1.44e30f;

  auto stage = [&](int buf, int kv0) {
    int r = t >> 3, c = t & 7;
    gl_lds16(Kg + ((size_t)(b * SS + kv0 + r)) * DD + h * HDIM + ((c ^ (r & 7)) * 8),
             lds + buf * 8192 + t * 16);
    gl_lds16(VTg + ((size_t)(bh * 64 + r)) * 2048 + kv0 + ((c ^ (r & 7)) * 8),
             lds + 16384 + buf * 8192 + t * 16);
    if (t < 64) *(float*)(lds + 32768 + buf * 256 + t * 4) = mask[b * SS + kv0 + t];
  };

  stage(0, 0);
  for (int it = 0; it < SS / 64; ++it) {
    __syncthreads();
    if (it + 1 < SS / 64) stage((it + 1) & 1, (it + 1) * 64);
    const char* Kb = lds + (it & 1) * 8192;
    const char* Vb = lds + 16384 + (it & 1) * 8192;
    const float* mk = (const float*)(lds + 32768 + (it & 1) * 256);

    f32x16 s0 = {}, s1 = {};
#pragma unroll
    for (int kc = 0; kc < 4; ++kc) {
      int c = kc * 2 + hi;
      int r0 = l31, r1 = 32 + l31;
      bf16x8 ka0 = *(const bf16x8*)(Kb + r0 * 128 + ((c ^ (r0 & 7)) << 4));
      bf16x8 ka1 = *(const bf16x8*)(Kb + r1 * 128 + ((c ^ (r1 & 7)) << 4));
      s0 = __builtin_amdgcn_mfma_f32_32x32x16_bf16(ka0, qf[kc], s0, 0, 0, 0);
      s1 = __builtin_amdgcn_mfma_f32_32x32x16_bf16(ka1, qf[kc], s1, 0, 0, 0);
    }
#pragma unroll
    for (int g = 0; g < 4; ++g) {
      float4 mg0 = *(const float4*)(mk + g * 8 + hi * 4);
      float4 mg1 = *(const float4*)(mk + 32 + g * 8 + hi * 4);
      const float* m0p = (const float*)&mg0;
      const float* m1p = (const float*)&mg1;
#pragma unroll
      for (int i = 0; i < 4; ++i) {
        s0[g * 4 + i] = fmaf(s0[g * 4 + i], 0.125f, m0p[i]);
        s1[g * 4 + i] = fmaf(s1[g * 4 + i], 0.125f, m1p[i]);
      }
    }
    float pmax;
    {
      f32x16 q8;
#pragma unroll
      for (int r = 0; r < 16; ++r) q8[r] = fmaxf(s0[r], s1[r]);
#pragma unroll
      for (int r = 0; r < 8; ++r) q8[r] = fmaxf(q8[r], q8[r + 8]);
#pragma unroll
      for (int r = 0; r < 4; ++r) q8[r] = fmaxf(q8[r], q8[r + 4]);
      pmax = fmaxf(fmaxf(q8[0], q8[1]), fmaxf(q8[2], q8[3]));
      pmax = fmaxf(pmax, __shfl_xor(pmax, 32));
    }
    if (__any(pmax > m + 8.0f)) {
      float mnew = fmaxf(m, pmax);
      float fac = EXP2((m - mnew) * LOG2E);
      l *= fac;
#pragma unroll
      for (int r = 0; r < 16; ++r) { ctx0[r] *= fac; ctx1[r] *= fac; }
      m = mnew;
      mC = m * LOG2E;
    }
    float rsA = 0.f, rsB = 0.f;
#pragma unroll
    for (int r = 0; r < 16; ++r) {
      s0[r] = EXP2(fmaf(s0[r], LOG2E, -mC));
      s1[r] = EXP2(fmaf(s1[r], LOG2E, -mC));
      rsA += s0[r];
      rsB += s1[r];
    }
    rsA += rsB;
    rsA += __shfl_xor(rsA, 32);
    l += rsA;

    unsigned W0[8], W1[8];
#pragma unroll
    for (int g = 0; g < 4; ++g) {
      W0[g * 2] = pk2(s0[g * 4 + 0], s0[g * 4 + 1]);
      W0[g * 2 + 1] = pk2(s0[g * 4 + 2], s0[g * 4 + 3]);
      W1[g * 2] = pk2(s1[g * 4 + 0], s1[g * 4 + 1]);
      W1[g * 2 + 1] = pk2(s1[g * 4 + 2], s1[g * 4 + 3]);
    }
    unsigned swA0 = __shfl_xor(hi ? W0[0] : W0[2], 32);
    unsigned swA1 = __shfl_xor(hi ? W0[1] : W0[3], 32);
    unsigned swB0 = __shfl_xor(hi ? W0[4] : W0[6], 32);
    unsigned swB1 = __shfl_xor(hi ? W0[5] : W0[7], 32);
    unsigned swC0 = __shfl_xor(hi ? W1[0] : W1[2], 32);
    unsigned swC1 = __shfl_xor(hi ? W1[1] : W1[3], 32);
    unsigned swD0 = __shfl_xor(hi ? W1[4] : W1[6], 32);
    unsigned swD1 = __shfl_xor(hi ? W1[5] : W1[7], 32);
    u32x4 pb[4];
    pb[0] = hi ? (u32x4){swA0, swA1, W0[2], W0[3]} : (u32x4){W0[0], W0[1], swA0, swA1};
    pb[1] = hi ? (u32x4){swB0, swB1, W0[6], W0[7]} : (u32x4){W0[4], W0[5], swB0, swB1};
    pb[2] = hi ? (u32x4){swC0, swC1, W1[2], W1[3]} : (u32x4){W1[0], W1[1], swC0, swC1};
    pb[3] = hi ? (u32x4){swD0, swD1, W1[6], W1[7]} : (u32x4){W1[4], W1[5], swD0, swD1};

#pragma unroll
    for (int kc = 0; kc < 4; ++kc) {
      bf16x8 pbf = __builtin_bit_cast(bf16x8, pb[kc]);
      int c = kc * 2 + hi;
      int r0 = l31, r1 = 32 + l31;
      bf16x8 va0 = *(const bf16x8*)(Vb + r0 * 128 + ((c ^ (r0 & 7)) << 4));
      bf16x8 va1 = *(const bf16x8*)(Vb + r1 * 128 + ((c ^ (r1 & 7)) << 4));
      ctx0 = __builtin_amdgcn_mfma_f32_32x32x16_bf16(va0, pbf, ctx0, 0, 0, 0);
      ctx1 = __builtin_amdgcn_mfma_f32_32x32x16_bf16(va1, pbf, ctx1, 0, 0, 0);
    }
  }

  float inv = 1.0f / l;
#pragma unroll
  for (int r = 0; r < 16; ++r) { ctx0[r] *= inv; ctx1[r] *= inv; }
  __syncthreads();
  {
    int row = w * 32 + l31;
#pragma unroll
    for (int dt = 0; dt < 2; ++dt) {
#pragma unroll
      for (int g = 0; g < 4; ++g) {
        unsigned lo2 = dt ? pk2(ctx1[g * 4 + 0], ctx1[g * 4 + 1]) : pk2(ctx0[g * 4 + 0], ctx0[g * 4 + 1]);
        unsigned hi2 = dt ? pk2(ctx1[g * 4 + 2], ctx1[g * 4 + 3]) : pk2(ctx0[g * 4 + 2], ctx0[g * 4 + 3]);
        int c = dt * 4 + g;
        *(uint2*)(lds + row * 128 + ((c ^ (row & 7)) << 4) + hi * 8) = make_uint2(lo2, hi2);
      }
    }
  }
  __syncthreads();
  {
    int r = t >> 1;
    size_t tok = (size_t)(b * SS + q0 + r);
#pragma unroll
    for (int i = 0; i < 4; ++i) {
      int c = (t & 1) * 4 + i;
      u32x4 vv = *(const u32x4*)(lds + r * 128 + ((c ^ (r & 7)) << 4));
      *(u32x4*)((short*)O + tok * DD + h * HDIM + c * 8) = vv;
    }
  }
}

// ---------------- host-side orchestration ------------------------------------
extern "C" void kernel_launch(void* const* d_in, const int* in_sizes, int n_in,
                              void* d_out, int out_size, void* d_ws, size_t ws_size,
                              hipStream_t stream) {
  const float* x = (const float*)d_in[0];
  const float* mask = (const float*)d_in[1];
  const float* wq = (const float*)d_in[2];
  const float* bq = (const float*)d_in[3];
  const float* wk = (const float*)d_in[4];
  const float* bk = (const float*)d_in[5];
  const float* wv = (const float*)d_in[6];
  const float* bv = (const float*)d_in[7];
  const float* wo = (const float*)d_in[8];
  const float* bo = (const float*)d_in[9];
  const float* w1 = (const float*)d_in[10];
  const float* b1 = (const float*)d_in[11];
  const float* w2 = (const float*)d_in[12];
  const float* b2 = (const float*)d_in[13];
  const float* g1 = (const float*)d_in[14];
  const float* be1 = (const float*)d_in[15];
  const float* g2 = (const float*)d_in[16];
  const float* be2 = (const float*)d_in[17];

  char* ws = (char*)d_ws;
  const size_t MB = 1024ull * 1024ull;
  __hip_bfloat16* wqkvT = (__hip_bfloat16*)(ws + 0 * MB);   // [3072][1024], 6MB
  __hip_bfloat16* woT = (__hip_bfloat16*)(ws + 6 * MB);     // 2MB
  __hip_bfloat16* w1T = (__hip_bfloat16*)(ws + 8 * MB);     // 8MB
  __hip_bfloat16* w2T = (__hip_bfloat16*)(ws + 16 * MB);    // 8MB
  __hip_bfloat16* xn = (__hip_bfloat16*)(ws + 24 * MB);     // 8MB; later h2
  __hip_bfloat16* qb = (__hip_bfloat16*)(ws + 32 * MB);
  __hip_bfloat16* kb = (__hip_bfloat16*)(ws + 40 * MB);
  __hip_bfloat16* vtb = (__hip_bfloat16*)(ws + 48 * MB);    // V^T [32][64][2048]
  __hip_bfloat16* ctxb = (__hip_bfloat16*)(ws + 56 * MB);
  float* h1 = (float*)(ws + 64 * MB);                       // 16MB
  __hip_bfloat16* h2 = xn;
  __hip_bfloat16* a1 = qb;                                  // 32MB @ 32..64
  // O-proj bf16 partials: 24,32,40,48 MB (xn,qb,kb,vtb dead at that point)
  // FF2 bf16 partials: 0, 8, 24 MB (weights/h2 dead at that point)

  convT<<<dim3(32, 32), 256, 0, stream>>>(wq, wqkvT, 1024, 1024);
  convT<<<dim3(32, 32), 256, 0, stream>>>(wk, wqkvT + 1024 * 1024, 1024, 1024);
  convT<<<dim3(32, 32), 256, 0, stream>>>(wv, wqkvT + 2 * 1024 * 1024, 1024, 1024);
  convT<<<dim3(32, 32), 256, 0, stream>>>(wo, woT, 1024, 1024);
  convT<<<dim3(128, 32), 256, 0, stream>>>(w1, w1T, 1024, 4096);
  convT<<<dim3(32, 128), 256, 0, stream>>>(w2, w2T, 4096, 1024);

  ln_bf16<<<1024, 256, 0, stream>>>(x, g1, be1, xn);

  // fused QKV: M=4096, N=3072, K=1024 -> 192 blocks
  gemm256<5><<<dim3(192, 1), 512, 0, stream>>>(
      xn, wqkvT, bq, bk, bv, qb, kb, vtb, NTOK, 3072, 1024, 12, 1);

  flash_attn2<<<dim3(8, 32), 512, 0, stream>>>(qb, kb, vtb, mask, ctxb);

  // O-proj split-K=4 -> bf16 partials @ 24+8z MB
  gemm256<6><<<dim3(64, 4), 512, 0, stream>>>(
      ctxb, woT, nullptr, nullptr, nullptr, ws, nullptr, nullptr, NTOK, 1024, 1024, 4, 4);

  reduce4<<<2048, 256, 0, stream>>>((__hip_bfloat16*)(ws + 24 * MB),
                                    (__hip_bfloat16*)(ws + 32 * MB),
                                    (__hip_bfloat16*)(ws + 40 * MB),
                                    (__hip_bfloat16*)(ws + 48 * MB),
                                    x, bo, h1);

  ln_bf16<<<1024, 256, 0, stream>>>(h1, g2, be2, h2);

  // FF1 + gelu: M=4096, N=4096 -> 256 blocks
  gemm256<1><<<dim3(256, 1), 512, 0, stream>>>(
      h2, w1T, b1, nullptr, nullptr, a1, nullptr, nullptr, NTOK, FFD, 1024, 16, 1);

  // FF2 split-K=3 -> bf16 partials @ 0/8/24 MB
  gemm256<4><<<dim3(64, 3), 512, 0, stream>>>(
      a1, w2T, nullptr, nullptr, nullptr, ws, nullptr, nullptr, NTOK, 1024, FFD, 4, 3);

  reduce3<<<2048, 256, 0, stream>>>((__hip_bfloat16*)(ws + 0 * MB),
                                    (__hip_bfloat16*)(ws + 8 * MB),
                                    (__hip_bfloat16*)(ws + 24 * MB),
                                    h1, b2, (float*)d_out);
}

// Round 5
// 285.840 us; speedup vs baseline: 1.2097x; 1.2097x over previous
//
#include <hip/hip_runtime.h>
#include <hip/hip_bf16.h>
#include <math.h>

// Transformer layer: B=2 S=2048 D=1024 H=16 HD=64 FF=4096, fp32 I/O.
// Heavy GEMMs: m97-style 128x128 bf16 MFMA tiles, >=3 blocks/CU via split-K.

#define BB 2
#define SS 2048
#define DD 1024
#define HH 16
#define HDIM 64
#define FFD 4096
#define NTOK (BB*SS)
#define LOG2E 1.4426950408889634f

typedef __attribute__((ext_vector_type(8))) short bf16x8;
typedef __attribute__((ext_vector_type(4))) float f32x4;
typedef __attribute__((ext_vector_type(16))) float f32x16;
typedef __attribute__((ext_vector_type(4))) unsigned int u32x4;

#if __has_builtin(__builtin_amdgcn_exp2f)
#define EXP2(x) __builtin_amdgcn_exp2f(x)
#else
#define EXP2(x) exp2f(x)
#endif

__device__ __forceinline__ void gl_lds16(const void* g, void* l) {
  __builtin_amdgcn_global_load_lds(
      (const __attribute__((address_space(1))) unsigned int*)g,
      (__attribute__((address_space(3))) unsigned int*)l, 16, 0, 0);
}

// RNE float->bf16 bits (finite inputs only)
__device__ __forceinline__ short f2bf(float f) {
  unsigned int u = __builtin_bit_cast(unsigned int, f);
  unsigned int r = (u + 0x7fffu + ((u >> 16) & 1u)) >> 16;
  return (short)r;
}
__device__ __forceinline__ unsigned pk2(float lo, float hi) {
  return (unsigned)(unsigned short)f2bf(lo) | ((unsigned)(unsigned short)f2bf(hi) << 16);
}

// ---------------- transpose + fp32->bf16 convert: wt[n][k] = bf16(w[k][n]) ----
__global__ __launch_bounds__(256) void convT(const float* __restrict__ w,
                                             __hip_bfloat16* __restrict__ wt,
                                             int K, int N) {
  __shared__ float tile[32][33];
  int k0 = blockIdx.y * 32, n0 = blockIdx.x * 32;
  int tx = threadIdx.x & 31, ty = threadIdx.x >> 5;
#pragma unroll
  for (int i = 0; i < 4; ++i) {
    int r = ty + i * 8;
    tile[r][tx] = w[(size_t)(k0 + r) * N + n0 + tx];
  }
  __syncthreads();
#pragma unroll
  for (int i = 0; i < 4; ++i) {
    int r = ty + i * 8;
    wt[(size_t)(n0 + r) * K + k0 + tx] = __float2bfloat16(tile[tx][r]);
  }
}

// ---------------- LayerNorm (fp32 in -> bf16 out), one wave per row ----------
__global__ __launch_bounds__(256) void ln_bf16(const float* __restrict__ x,
                                               const float* __restrict__ g,
                                               const float* __restrict__ be,
                                               __hip_bfloat16* __restrict__ out) {
  int w = threadIdx.x >> 6, lane = threadIdx.x & 63;
  int row = blockIdx.x * 4 + w;
  const float* xr = x + (size_t)row * DD;
  float4 v[4];
  float sum = 0.f, sq = 0.f;
#pragma unroll
  for (int i = 0; i < 4; ++i) {
    v[i] = *(const float4*)(xr + lane * 4 + i * 256);
    sum += v[i].x + v[i].y + v[i].z + v[i].w;
    sq += v[i].x * v[i].x + v[i].y * v[i].y + v[i].z * v[i].z + v[i].w * v[i].w;
  }
#pragma unroll
  for (int off = 1; off < 64; off <<= 1) {
    sum += __shfl_xor(sum, off);
    sq += __shfl_xor(sq, off);
  }
  float mu = sum * (1.f / 1024.f);
  float var = sq * (1.f / 1024.f) - mu * mu;
  float rs = rsqrtf(var + 1e-12f);
  __hip_bfloat16* orow = out + (size_t)row * DD;
#pragma unroll
  for (int i = 0; i < 4; ++i) {
    int c = lane * 4 + i * 256;
    float4 gg = *(const float4*)(g + c);
    float4 bb = *(const float4*)(be + c);
    short4 o;
    o.x = f2bf((v[i].x - mu) * rs * gg.x + bb.x);
    o.y = f2bf((v[i].y - mu) * rs * gg.y + bb.y);
    o.z = f2bf((v[i].z - mu) * rs * gg.z + bb.z);
    o.w = f2bf((v[i].w - mu) * rs * gg.w + bb.w);
    *(short4*)((short*)orow + c) = o;
  }
}

// ---------------- GEMM: C[M,N] = A[M,K] (bf16) * BT[N,K]^T + epilogue --------
// m97 structure: 128x128 tile, BK=32, 4 waves, 16KB LDS, gl_lds16 width 16.
// blockIdx.z = split-K slice (kSplit slices over K).
// EPI 1: +bias, gelu-erf -> bf16             [FF1]
// EPI 5: QKV fused (N=3072): Q,K +bias -> bf16; V +bias -> bf16 transposed
// EPI 7: raw -> bf16 partial @ C0 + z*4Mi elems        [O-proj split-K]
// EPI 8: raw -> bf16 partial @ C0 + {0,4Mi,12Mi} elems [FF2 split-K]
template <int EPI>
__global__ __launch_bounds__(256, 4) void gemm_bt(
    const __hip_bfloat16* __restrict__ A, const __hip_bfloat16* __restrict__ BT,
    const float* __restrict__ bA, const float* __restrict__ bB,
    const float* __restrict__ bC,
    void* __restrict__ C0, void* __restrict__ C1, void* __restrict__ C2,
    int M, int N, int K, int kSplit) {
  __shared__ __align__(16) short As[128 * 32];
  __shared__ __align__(16) short Bs[128 * 32];
  const int t = threadIdx.x, lane = t & 63, w = t >> 6;
  const int m0 = blockIdx.y * 128, n0 = blockIdx.x * 128;
  const int wm = (w >> 1) * 64, wn = (w & 1) * 64;
  const int row16 = lane & 15, grp = lane >> 4;
  const int arow = t >> 2, achunk = t & 3;
  f32x4 acc[4][4] = {};

  const int steps = K >> 5;
  const int z = blockIdx.z;
  const int sBeg = (z * steps) / kSplit, sEnd = ((z + 1) * steps) / kSplit;

  for (int s = sBeg; s < sEnd; ++s) {
    const int kt = s << 5;
    __syncthreads();
#pragma unroll
    for (int j = 0; j < 2; ++j) {
      int r = arow + j * 64;
      gl_lds16(A + (size_t)(m0 + r) * K + kt + achunk * 8,
               (char*)As + r * 64 + achunk * 16);
      gl_lds16(BT + (size_t)(n0 + r) * K + kt + achunk * 8,
               (char*)Bs + r * 64 + achunk * 16);
    }
    __syncthreads();
    bf16x8 af[4], bfr[4];
#pragma unroll
    for (int f = 0; f < 4; ++f) {
      af[f] = *(const bf16x8*)((const char*)As + (wm + f * 16 + row16) * 64 + grp * 16);
      bfr[f] = *(const bf16x8*)((const char*)Bs + (wn + f * 16 + row16) * 64 + grp * 16);
    }
#pragma unroll
    for (int mf = 0; mf < 4; ++mf)
#pragma unroll
      for (int nf = 0; nf < 4; ++nf)
        acc[mf][nf] =
            __builtin_amdgcn_mfma_f32_16x16x32_bf16(af[mf], bfr[nf], acc[mf][nf], 0, 0, 0);
  }

  // ---------------- epilogues ----------------
  if constexpr (EPI == 5) {
    if (n0 >= 2048) {  // V: +bias, bf16, transposed per-batch -> C2
#pragma unroll
      for (int nf = 0; nf < 4; ++nf) {
        int nv = n0 - 2048 + wn + nf * 16 + row16;
        float bv = bC[nv];
#pragma unroll
        for (int mf = 0; mf < 4; ++mf) {
          int tokB = m0 + wm + mf * 16 + grp * 4;
          int vr = ((tokB >> 11) << 10) + nv;
          f32x4 a = acc[mf][nf];
          uint2 val = make_uint2(pk2(a[0] + bv, a[1] + bv), pk2(a[2] + bv, a[3] + bv));
          *(uint2*)((__hip_bfloat16*)C2 + (size_t)vr * 2048 + (tokB & 2047)) = val;
        }
      }
      return;
    }
    // Q or K: +bias -> bf16, ld 1024
    const bool isK = n0 >= 1024;
    __hip_bfloat16* outP = (__hip_bfloat16*)(isK ? C1 : C0);
    const float* bp = isK ? bB : bA;
    int colB = n0 & 1023;
#pragma unroll
    for (int nf = 0; nf < 4; ++nf) {
      int n = colB + wn + nf * 16 + row16;
      float bv = bp[n];
#pragma unroll
      for (int mf = 0; mf < 4; ++mf)
#pragma unroll
        for (int r = 0; r < 4; ++r) {
          int m = m0 + wm + mf * 16 + grp * 4 + r;
          outP[(size_t)m * 1024 + n] = __float2bfloat16(acc[mf][nf][r] + bv);
        }
    }
    return;
  }

  if constexpr (EPI == 1) {  // +bias, gelu -> bf16
#pragma unroll
    for (int nf = 0; nf < 4; ++nf) {
      int n = n0 + wn + nf * 16 + row16;
      float bv = bA[n];
#pragma unroll
      for (int mf = 0; mf < 4; ++mf)
#pragma unroll
        for (int r = 0; r < 4; ++r) {
          int m = m0 + wm + mf * 16 + grp * 4 + r;
          float val = acc[mf][nf][r] + bv;
          val = 0.5f * val * (1.0f + erff(val * 0.70710678118654752f));
          ((__hip_bfloat16*)C0)[(size_t)m * N + n] = __float2bfloat16(val);
        }
    }
    return;
  }

  if constexpr (EPI == 7 || EPI == 8) {  // raw -> bf16 partial
    size_t off;
    if constexpr (EPI == 7) off = (size_t)z * 4194304ull;
    else off = (z == 0) ? 0ull : ((z == 1) ? 4194304ull : 12582912ull);
    __hip_bfloat16* outP = (__hip_bfloat16*)C0 + off;
#pragma unroll
    for (int nf = 0; nf < 4; ++nf) {
      int n = n0 + wn + nf * 16 + row16;
#pragma unroll
      for (int mf = 0; mf < 4; ++mf)
#pragma unroll
        for (int r = 0; r < 4; ++r) {
          int m = m0 + wm + mf * 16 + grp * 4 + r;
          outP[(size_t)m * N + n] = __float2bfloat16(acc[mf][nf][r]);
        }
    }
  }
}

// ---------------- FF2 split-K reduce: out = h1 + b2 + sum(3 partials) --------
__global__ __launch_bounds__(256) void reduce3(const __hip_bfloat16* __restrict__ p0,
                                               const __hip_bfloat16* __restrict__ p1,
                                               const __hip_bfloat16* __restrict__ p2,
                                               const float* __restrict__ h1,
                                               const float* __restrict__ b2,
                                               float* __restrict__ out) {
  int idx = (blockIdx.x * 256 + threadIdx.x) * 8;
  int n = idx & 1023;
  bf16x8 a = *(const bf16x8*)(p0 + idx);
  bf16x8 b = *(const bf16x8*)(p1 + idx);
  bf16x8 c = *(const bf16x8*)(p2 + idx);
  float4 hA = *(const float4*)(h1 + idx), hB = *(const float4*)(h1 + idx + 4);
  float4 bA = *(const float4*)(b2 + n), bB = *(const float4*)(b2 + n + 4);
  float o[8];
#pragma unroll
  for (int j = 0; j < 8; ++j) {
    float fa = __builtin_bit_cast(float, ((unsigned)(unsigned short)a[j]) << 16);
    float fb = __builtin_bit_cast(float, ((unsigned)(unsigned short)b[j]) << 16);
    float fc = __builtin_bit_cast(float, ((unsigned)(unsigned short)c[j]) << 16);
    o[j] = fa + fb + fc;
  }
  float4 r0 = make_float4(o[0] + hA.x + bA.x, o[1] + hA.y + bA.y,
                          o[2] + hA.z + bA.z, o[3] + hA.w + bA.w);
  float4 r1 = make_float4(o[4] + hB.x + bB.x, o[5] + hB.y + bB.y,
                          o[6] + hB.z + bB.z, o[7] + hB.w + bB.w);
  *(float4*)(out + idx) = r0;
  *(float4*)(out + idx + 4) = r1;
}

// ---------------- O-proj split-K reduce: h1 = x + bo + sum(4 partials) -------
__global__ __launch_bounds__(256) void reduce4(const __hip_bfloat16* __restrict__ p0,
                                               const __hip_bfloat16* __restrict__ p1,
                                               const __hip_bfloat16* __restrict__ p2,
                                               const __hip_bfloat16* __restrict__ p3,
                                               const float* __restrict__ x,
                                               const float* __restrict__ bo,
                                               float* __restrict__ out) {
  int idx = (blockIdx.x * 256 + threadIdx.x) * 8;
  int n = idx & 1023;
  bf16x8 a = *(const bf16x8*)(p0 + idx);
  bf16x8 b = *(const bf16x8*)(p1 + idx);
  bf16x8 c = *(const bf16x8*)(p2 + idx);
  bf16x8 d = *(const bf16x8*)(p3 + idx);
  float4 hA = *(const float4*)(x + idx), hB = *(const float4*)(x + idx + 4);
  float4 bA = *(const float4*)(bo + n), bB = *(const float4*)(bo + n + 4);
  float o[8];
#pragma unroll
  for (int j = 0; j < 8; ++j) {
    float fa = __builtin_bit_cast(float, ((unsigned)(unsigned short)a[j]) << 16);
    float fb = __builtin_bit_cast(float, ((unsigned)(unsigned short)b[j]) << 16);
    float fc = __builtin_bit_cast(float, ((unsigned)(unsigned short)c[j]) << 16);
    float fd = __builtin_bit_cast(float, ((unsigned)(unsigned short)d[j]) << 16);
    o[j] = (fa + fb) + (fc + fd);
  }
  float4 r0 = make_float4(o[0] + hA.x + bA.x, o[1] + hA.y + bA.y,
                          o[2] + hA.z + bA.z, o[3] + hA.w + bA.w);
  float4 r1 = make_float4(o[4] + hB.x + bB.x, o[5] + hB.y + bB.y,
                          o[6] + hB.z + bB.z, o[7] + hB.w + bB.w);
  *(float4*)(out + idx) = r0;
  *(float4*)(out + idx + 4) = r1;
}

// ---------------- Flash attention v2 (verified) ------------------------------
__global__ __launch_bounds__(512) void flash_attn2(
    const __hip_bfloat16* __restrict__ Q,
    const __hip_bfloat16* __restrict__ Kg,
    const __hip_bfloat16* __restrict__ VTg,
    const float* __restrict__ mask,
    __hip_bfloat16* __restrict__ O) {
  __shared__ __align__(16) char lds[33280];
  const int t = threadIdx.x, lane = t & 63, w = t >> 6;
  const int l31 = lane & 31, hi = lane >> 5;
  const int q0 = blockIdx.x * 256;
  const int bh = blockIdx.y, b = bh >> 4, h = bh & 15;
  const int qrow = q0 + w * 32 + l31;

  bf16x8 qf[4];
  {
    const __hip_bfloat16* qp = Q + ((size_t)(b * SS + qrow)) * DD + h * HDIM + hi * 8;
    qf[0] = *(const bf16x8*)(qp);
    qf[1] = *(const bf16x8*)(qp + 16);
    qf[2] = *(const bf16x8*)(qp + 32);
    qf[3] = *(const bf16x8*)(qp + 48);
  }
  f32x16 ctx0 = {}, ctx1 = {};
  float m = -1e30f, l = 0.f, mC = -1.44e30f;

  auto stage = [&](int buf, int kv0) {
    int r = t >> 3, c = t & 7;
    gl_lds16(Kg + ((size_t)(b * SS + kv0 + r)) * DD + h * HDIM + ((c ^ (r & 7)) * 8),
             lds + buf * 8192 + t * 16);
    gl_lds16(VTg + ((size_t)(bh * 64 + r)) * 2048 + kv0 + ((c ^ (r & 7)) * 8),
             lds + 16384 + buf * 8192 + t * 16);
    if (t < 64) *(float*)(lds + 32768 + buf * 256 + t * 4) = mask[b * SS + kv0 + t];
  };

  stage(0, 0);
  for (int it = 0; it < SS / 64; ++it) {
    __syncthreads();
    if (it + 1 < SS / 64) stage((it + 1) & 1, (it + 1) * 64);
    const char* Kb = lds + (it & 1) * 8192;
    const char* Vb = lds + 16384 + (it & 1) * 8192;
    const float* mk = (const float*)(lds + 32768 + (it & 1) * 256);

    f32x16 s0 = {}, s1 = {};
#pragma unroll
    for (int kc = 0; kc < 4; ++kc) {
      int c = kc * 2 + hi;
      int r0 = l31, r1 = 32 + l31;
      bf16x8 ka0 = *(const bf16x8*)(Kb + r0 * 128 + ((c ^ (r0 & 7)) << 4));
      bf16x8 ka1 = *(const bf16x8*)(Kb + r1 * 128 + ((c ^ (r1 & 7)) << 4));
      s0 = __builtin_amdgcn_mfma_f32_32x32x16_bf16(ka0, qf[kc], s0, 0, 0, 0);
      s1 = __builtin_amdgcn_mfma_f32_32x32x16_bf16(ka1, qf[kc], s1, 0, 0, 0);
    }
#pragma unroll
    for (int g = 0; g < 4; ++g) {
      float4 mg0 = *(const float4*)(mk + g * 8 + hi * 4);
      float4 mg1 = *(const float4*)(mk + 32 + g * 8 + hi * 4);
      const float* m0p = (const float*)&mg0;
      const float* m1p = (const float*)&mg1;
#pragma unroll
      for (int i = 0; i < 4; ++i) {
        s0[g * 4 + i] = fmaf(s0[g * 4 + i], 0.125f, m0p[i]);
        s1[g * 4 + i] = fmaf(s1[g * 4 + i], 0.125f, m1p[i]);
      }
    }
    float pmax;
    {
      f32x16 q8;
#pragma unroll
      for (int r = 0; r < 16; ++r) q8[r] = fmaxf(s0[r], s1[r]);
#pragma unroll
      for (int r = 0; r < 8; ++r) q8[r] = fmaxf(q8[r], q8[r + 8]);
#pragma unroll
      for (int r = 0; r < 4; ++r) q8[r] = fmaxf(q8[r], q8[r + 4]);
      pmax = fmaxf(fmaxf(q8[0], q8[1]), fmaxf(q8[2], q8[3]));
      pmax = fmaxf(pmax, __shfl_xor(pmax, 32));
    }
    if (__any(pmax > m + 8.0f)) {
      float mnew = fmaxf(m, pmax);
      float fac = EXP2((m - mnew) * LOG2E);
      l *= fac;
#pragma unroll
      for (int r = 0; r < 16; ++r) { ctx0[r] *= fac; ctx1[r] *= fac; }
      m = mnew;
      mC = m * LOG2E;
    }
    float rsA = 0.f, rsB = 0.f;
#pragma unroll
    for (int r = 0; r < 16; ++r) {
      s0[r] = EXP2(fmaf(s0[r], LOG2E, -mC));
      s1[r] = EXP2(fmaf(s1[r], LOG2E, -mC));
      rsA += s0[r];
      rsB += s1[r];
    }
    rsA += rsB;
    rsA += __shfl_xor(rsA, 32);
    l += rsA;

    unsigned W0[8], W1[8];
#pragma unroll
    for (int g = 0; g < 4; ++g) {
      W0[g * 2] = pk2(s0[g * 4 + 0], s0[g * 4 + 1]);
      W0[g * 2 + 1] = pk2(s0[g * 4 + 2], s0[g * 4 + 3]);
      W1[g * 2] = pk2(s1[g * 4 + 0], s1[g * 4 + 1]);
      W1[g * 2 + 1] = pk2(s1[g * 4 + 2], s1[g * 4 + 3]);
    }
    unsigned swA0 = __shfl_xor(hi ? W0[0] : W0[2], 32);
    unsigned swA1 = __shfl_xor(hi ? W0[1] : W0[3], 32);
    unsigned swB0 = __shfl_xor(hi ? W0[4] : W0[6], 32);
    unsigned swB1 = __shfl_xor(hi ? W0[5] : W0[7], 32);
    unsigned swC0 = __shfl_xor(hi ? W1[0] : W1[2], 32);
    unsigned swC1 = __shfl_xor(hi ? W1[1] : W1[3], 32);
    unsigned swD0 = __shfl_xor(hi ? W1[4] : W1[6], 32);
    unsigned swD1 = __shfl_xor(hi ? W1[5] : W1[7], 32);
    u32x4 pb[4];
    pb[0] = hi ? (u32x4){swA0, swA1, W0[2], W0[3]} : (u32x4){W0[0], W0[1], swA0, swA1};
    pb[1] = hi ? (u32x4){swB0, swB1, W0[6], W0[7]} : (u32x4){W0[4], W0[5], swB0, swB1};
    pb[2] = hi ? (u32x4){swC0, swC1, W1[2], W1[3]} : (u32x4){W1[0], W1[1], swC0, swC1};
    pb[3] = hi ? (u32x4){swD0, swD1, W1[6], W1[7]} : (u32x4){W1[4], W1[5], swD0, swD1};

#pragma unroll
    for (int kc = 0; kc < 4; ++kc) {
      bf16x8 pbf = __builtin_bit_cast(bf16x8, pb[kc]);
      int c = kc * 2 + hi;
      int r0 = l31, r1 = 32 + l31;
      bf16x8 va0 = *(const bf16x8*)(Vb + r0 * 128 + ((c ^ (r0 & 7)) << 4));
      bf16x8 va1 = *(const bf16x8*)(Vb + r1 * 128 + ((c ^ (r1 & 7)) << 4));
      ctx0 = __builtin_amdgcn_mfma_f32_32x32x16_bf16(va0, pbf, ctx0, 0, 0, 0);
      ctx1 = __builtin_amdgcn_mfma_f32_32x32x16_bf16(va1, pbf, ctx1, 0, 0, 0);
    }
  }

  float inv = 1.0f / l;
#pragma unroll
  for (int r = 0; r < 16; ++r) { ctx0[r] *= inv; ctx1[r] *= inv; }
  __syncthreads();
  {
    int row = w * 32 + l31;
#pragma unroll
    for (int dt = 0; dt < 2; ++dt) {
#pragma unroll
      for (int g = 0; g < 4; ++g) {
        unsigned lo2 = dt ? pk2(ctx1[g * 4 + 0], ctx1[g * 4 + 1]) : pk2(ctx0[g * 4 + 0], ctx0[g * 4 + 1]);
        unsigned hi2 = dt ? pk2(ctx1[g * 4 + 2], ctx1[g * 4 + 3]) : pk2(ctx0[g * 4 + 2], ctx0[g * 4 + 3]);
        int c = dt * 4 + g;
        *(uint2*)(lds + row * 128 + ((c ^ (row & 7)) << 4) + hi * 8) = make_uint2(lo2, hi2);
      }
    }
  }
  __syncthreads();
  {
    int r = t >> 1;
    size_t tok = (size_t)(b * SS + q0 + r);
#pragma unroll
    for (int i = 0; i < 4; ++i) {
      int c = (t & 1) * 4 + i;
      u32x4 vv = *(const u32x4*)(lds + r * 128 + ((c ^ (r & 7)) << 4));
      *(u32x4*)((short*)O + tok * DD + h * HDIM + c * 8) = vv;
    }
  }
}

// ---------------- host-side orchestration ------------------------------------
extern "C" void kernel_launch(void* const* d_in, const int* in_sizes, int n_in,
                              void* d_out, int out_size, void* d_ws, size_t ws_size,
                              hipStream_t stream) {
  const float* x = (const float*)d_in[0];
  const float* mask = (const float*)d_in[1];
  const float* wq = (const float*)d_in[2];
  const float* bq = (const float*)d_in[3];
  const float* wk = (const float*)d_in[4];
  const float* bk = (const float*)d_in[5];
  const float* wv = (const float*)d_in[6];
  const float* bv = (const float*)d_in[7];
  const float* wo = (const float*)d_in[8];
  const float* bo = (const float*)d_in[9];
  const float* w1 = (const float*)d_in[10];
  const float* b1 = (const float*)d_in[11];
  const float* w2 = (const float*)d_in[12];
  const float* b2 = (const float*)d_in[13];
  const float* g1 = (const float*)d_in[14];
  const float* be1 = (const float*)d_in[15];
  const float* g2 = (const float*)d_in[16];
  const float* be2 = (const float*)d_in[17];

  char* ws = (char*)d_ws;
  const size_t MB = 1024ull * 1024ull;
  __hip_bfloat16* wqkvT = (__hip_bfloat16*)(ws + 0 * MB);   // [3072][1024], 6MB
  __hip_bfloat16* woT = (__hip_bfloat16*)(ws + 6 * MB);     // 2MB
  __hip_bfloat16* w1T = (__hip_bfloat16*)(ws + 8 * MB);     // 8MB
  __hip_bfloat16* w2T = (__hip_bfloat16*)(ws + 16 * MB);    // 8MB
  __hip_bfloat16* xn = (__hip_bfloat16*)(ws + 24 * MB);     // 8MB; later h2
  __hip_bfloat16* qb = (__hip_bfloat16*)(ws + 32 * MB);
  __hip_bfloat16* kb = (__hip_bfloat16*)(ws + 40 * MB);
  __hip_bfloat16* vtb = (__hip_bfloat16*)(ws + 48 * MB);    // V^T [32][64][2048]
  __hip_bfloat16* ctxb = (__hip_bfloat16*)(ws + 56 * MB);
  float* h1 = (float*)(ws + 64 * MB);                       // 16MB
  __hip_bfloat16* h2 = xn;
  __hip_bfloat16* a1 = qb;                                  // 32MB @ 32..64
  // O-proj bf16 partials: 24,32,40,48 MB (xn,qb,kb,vtb dead at that point)
  // FF2 bf16 partials: 0, 8, 24 MB (weights/h2 dead at that point)

  convT<<<dim3(32, 32), 256, 0, stream>>>(wq, wqkvT, 1024, 1024);
  convT<<<dim3(32, 32), 256, 0, stream>>>(wk, wqkvT + 1024 * 1024, 1024, 1024);
  convT<<<dim3(32, 32), 256, 0, stream>>>(wv, wqkvT + 2 * 1024 * 1024, 1024, 1024);
  convT<<<dim3(32, 32), 256, 0, stream>>>(wo, woT, 1024, 1024);
  convT<<<dim3(128, 32), 256, 0, stream>>>(w1, w1T, 1024, 4096);
  convT<<<dim3(32, 128), 256, 0, stream>>>(w2, w2T, 4096, 1024);

  ln_bf16<<<1024, 256, 0, stream>>>(x, g1, be1, xn);

  // fused QKV: M=4096, N=3072, K=1024 -> 768 blocks (3/CU)
  gemm_bt<5><<<dim3(24, 32), 256, 0, stream>>>(
      xn, wqkvT, bq, bk, bv, qb, kb, vtb, NTOK, 3072, 1024, 1);

  flash_attn2<<<dim3(8, 32), 512, 0, stream>>>(qb, kb, vtb, mask, ctxb);

  // O-proj split-K=4 -> bf16 partials @ 24+8z MB (1024 blocks)
  gemm_bt<7><<<dim3(8, 32, 4), 256, 0, stream>>>(
      ctxb, woT, nullptr, nullptr, nullptr, ws + 24 * MB, nullptr, nullptr,
      NTOK, 1024, 1024, 4);

  reduce4<<<2048, 256, 0, stream>>>((__hip_bfloat16*)(ws + 24 * MB),
                                    (__hip_bfloat16*)(ws + 32 * MB),
                                    (__hip_bfloat16*)(ws + 40 * MB),
                                    (__hip_bfloat16*)(ws + 48 * MB),
                                    x, bo, h1);

  ln_bf16<<<1024, 256, 0, stream>>>(h1, g2, be2, h2);

  // FF1 + gelu: M=4096, N=4096, K=1024 -> 1024 blocks (4/CU)
  gemm_bt<1><<<dim3(32, 32), 256, 0, stream>>>(
      h2, w1T, b1, nullptr, nullptr, a1, nullptr, nullptr, NTOK, FFD, 1024, 1);

  // FF2 split-K=3 -> bf16 partials @ 0/8/24 MB (768 blocks)
  gemm_bt<8><<<dim3(8, 32, 3), 256, 0, stream>>>(
      a1, w2T, nullptr, nullptr, nullptr, ws, nullptr, nullptr,
      NTOK, 1024, FFD, 3);

  reduce3<<<2048, 256, 0, stream>>>((__hip_bfloat16*)(ws + 0 * MB),
                                    (__hip_bfloat16*)(ws + 8 * MB),
                                    (__hip_bfloat16*)(ws + 24 * MB),
                                    h1, b2, (float*)d_out);
}

// Round 6
// 284.856 us; speedup vs baseline: 1.2139x; 1.0035x over previous
//
#include <hip/hip_runtime.h>
#include <hip/hip_bf16.h>
#include <math.h>

// Transformer layer: B=2 S=2048 D=1024 H=16 HD=64 FF=4096, fp32 I/O.
// Heavy GEMMs: m97-style 128x128 bf16 MFMA tiles, >=3 blocks/CU via split-K,
// coalesced epilogues via 34KB LDS bounce.

#define BB 2
#define SS 2048
#define DD 1024
#define HH 16
#define HDIM 64
#define FFD 4096
#define NTOK (BB*SS)
#define LOG2E 1.4426950408889634f

typedef __attribute__((ext_vector_type(8))) short bf16x8;
typedef __attribute__((ext_vector_type(4))) float f32x4;
typedef __attribute__((ext_vector_type(16))) float f32x16;
typedef __attribute__((ext_vector_type(4))) unsigned int u32x4;

#if __has_builtin(__builtin_amdgcn_exp2f)
#define EXP2(x) __builtin_amdgcn_exp2f(x)
#else
#define EXP2(x) exp2f(x)
#endif

__device__ __forceinline__ void gl_lds16(const void* g, void* l) {
  __builtin_amdgcn_global_load_lds(
      (const __attribute__((address_space(1))) unsigned int*)g,
      (__attribute__((address_space(3))) unsigned int*)l, 16, 0, 0);
}

// RNE float->bf16 bits (finite inputs only)
__device__ __forceinline__ short f2bf(float f) {
  unsigned int u = __builtin_bit_cast(unsigned int, f);
  unsigned int r = (u + 0x7fffu + ((u >> 16) & 1u)) >> 16;
  return (short)r;
}
__device__ __forceinline__ unsigned pk2(float lo, float hi) {
  return (unsigned)(unsigned short)f2bf(lo) | ((unsigned)(unsigned short)f2bf(hi) << 16);
}

// ---------------- transpose + fp32->bf16 convert: wt[n][k] = bf16(w[k][n]) ----
__global__ __launch_bounds__(256) void convT(const float* __restrict__ w,
                                             __hip_bfloat16* __restrict__ wt,
                                             int K, int N) {
  __shared__ float tile[32][33];
  int k0 = blockIdx.y * 32, n0 = blockIdx.x * 32;
  int tx = threadIdx.x & 31, ty = threadIdx.x >> 5;
#pragma unroll
  for (int i = 0; i < 4; ++i) {
    int r = ty + i * 8;
    tile[r][tx] = w[(size_t)(k0 + r) * N + n0 + tx];
  }
  __syncthreads();
#pragma unroll
  for (int i = 0; i < 4; ++i) {
    int r = ty + i * 8;
    wt[(size_t)(n0 + r) * K + k0 + tx] = __float2bfloat16(tile[tx][r]);
  }
}

// ---------------- LayerNorm (fp32 in -> bf16 out), one wave per row ----------
__global__ __launch_bounds__(256) void ln_bf16(const float* __restrict__ x,
                                               const float* __restrict__ g,
                                               const float* __restrict__ be,
                                               __hip_bfloat16* __restrict__ out) {
  int w = threadIdx.x >> 6, lane = threadIdx.x & 63;
  int row = blockIdx.x * 4 + w;
  const float* xr = x + (size_t)row * DD;
  float4 v[4];
  float sum = 0.f, sq = 0.f;
#pragma unroll
  for (int i = 0; i < 4; ++i) {
    v[i] = *(const float4*)(xr + lane * 4 + i * 256);
    sum += v[i].x + v[i].y + v[i].z + v[i].w;
    sq += v[i].x * v[i].x + v[i].y * v[i].y + v[i].z * v[i].z + v[i].w * v[i].w;
  }
#pragma unroll
  for (int off = 1; off < 64; off <<= 1) {
    sum += __shfl_xor(sum, off);
    sq += __shfl_xor(sq, off);
  }
  float mu = sum * (1.f / 1024.f);
  float var = sq * (1.f / 1024.f) - mu * mu;
  float rs = rsqrtf(var + 1e-12f);
  __hip_bfloat16* orow = out + (size_t)row * DD;
#pragma unroll
  for (int i = 0; i < 4; ++i) {
    int c = lane * 4 + i * 256;
    float4 gg = *(const float4*)(g + c);
    float4 bb = *(const float4*)(be + c);
    short4 o;
    o.x = f2bf((v[i].x - mu) * rs * gg.x + bb.x);
    o.y = f2bf((v[i].y - mu) * rs * gg.y + bb.y);
    o.z = f2bf((v[i].z - mu) * rs * gg.z + bb.z);
    o.w = f2bf((v[i].w - mu) * rs * gg.w + bb.w);
    *(short4*)((short*)orow + c) = o;
  }
}

// ---------------- GEMM: C[M,N] = A[M,K] (bf16) * BT[N,K]^T + epilogue --------
// m97 structure: 128x128 tile, BK=32, 4 waves, gl_lds16 width 16.
// Epilogues bounce through LDS (272B-stride rows) for coalesced 16B stores.
// blockIdx.z = split-K slice.
// EPI 1: +bias, gelu-erf -> bf16                       [FF1]
// EPI 5: QKV fused (N=3072): Q,K +bias -> bf16; V +bias -> bf16 transposed
// EPI 7: raw -> bf16 partial @ C0 + z*4Mi elems        [O-proj split-K]
// EPI 8: raw -> bf16 partial @ C0 + {0,4Mi,12Mi} elems [FF2 split-K]
template <int EPI>
__global__ __launch_bounds__(256, 4) void gemm_bt(
    const __hip_bfloat16* __restrict__ A, const __hip_bfloat16* __restrict__ BT,
    const float* __restrict__ bA, const float* __restrict__ bB,
    const float* __restrict__ bC,
    void* __restrict__ C0, void* __restrict__ C1, void* __restrict__ C2,
    int M, int N, int K, int kSplit) {
  __shared__ __align__(16) char smem[34816];  // As@0 (8KB), Bs@8KB; epilogue arena
  short* As = (short*)smem;
  short* Bs = (short*)(smem + 8192);
  const int t = threadIdx.x, lane = t & 63, w = t >> 6;
  const int m0 = blockIdx.y * 128, n0 = blockIdx.x * 128;
  const int wm = (w >> 1) * 64, wn = (w & 1) * 64;
  const int row16 = lane & 15, grp = lane >> 4;
  const int arow = t >> 2, achunk = t & 3;
  f32x4 acc[4][4] = {};

  const int steps = K >> 5;
  const int z = blockIdx.z;
  const int sBeg = (z * steps) / kSplit, sEnd = ((z + 1) * steps) / kSplit;

  for (int s = sBeg; s < sEnd; ++s) {
    const int kt = s << 5;
    __syncthreads();
#pragma unroll
    for (int j = 0; j < 2; ++j) {
      int r = arow + j * 64;
      gl_lds16(A + (size_t)(m0 + r) * K + kt + achunk * 8,
               (char*)As + r * 64 + achunk * 16);
      gl_lds16(BT + (size_t)(n0 + r) * K + kt + achunk * 8,
               (char*)Bs + r * 64 + achunk * 16);
    }
    __syncthreads();
    bf16x8 af[4], bfr[4];
#pragma unroll
    for (int f = 0; f < 4; ++f) {
      af[f] = *(const bf16x8*)((const char*)As + (wm + f * 16 + row16) * 64 + grp * 16);
      bfr[f] = *(const bf16x8*)((const char*)Bs + (wn + f * 16 + row16) * 64 + grp * 16);
    }
#pragma unroll
    for (int mf = 0; mf < 4; ++mf)
#pragma unroll
      for (int nf = 0; nf < 4; ++nf)
        acc[mf][nf] =
            __builtin_amdgcn_mfma_f32_16x16x32_bf16(af[mf], bfr[nf], acc[mf][nf], 0, 0, 0);
  }

  __syncthreads();  // all LDS reads done before epilogue overwrites the arena

  // ---------------- V section of QKV: transposed bounce ----------------
  if constexpr (EPI == 5) {
    if (n0 >= 2048) {
#pragma unroll
      for (int nf = 0; nf < 4; ++nf) {
        int vloc = wn + nf * 16 + row16;           // local vr 0..127
        float bv = bC[n0 - 2048 + vloc];
#pragma unroll
        for (int mf = 0; mf < 4; ++mf) {
          int tloc = wm + mf * 16 + grp * 4;       // local token 0..124
          f32x4 a = acc[mf][nf];
          *(uint2*)(smem + vloc * 272 + tloc * 2) =
              make_uint2(pk2(a[0] + bv, a[1] + bv), pk2(a[2] + bv, a[3] + bv));
        }
      }
      __syncthreads();
      int vrBase = ((m0 >> 11) << 10) + (n0 - 2048);
      int mcol = m0 & 2047;
#pragma unroll
      for (int i = 0; i < 8; ++i) {
        int c = t + i * 256;
        int vr = c >> 4, tc = c & 15;
        u32x4 vv = *(const u32x4*)(smem + vr * 272 + tc * 16);
        *(u32x4*)((__hip_bfloat16*)C2 + (size_t)(vrBase + vr) * 2048 + mcol + tc * 8) = vv;
      }
      return;
    }
  }

  // ---------------- row-major bounce (EPI 1, 5-Q/K, 7, 8) ----------------
  __hip_bfloat16* outP = nullptr;
  int ldO = N, colB = n0;
  const float* bp = nullptr;
  if constexpr (EPI == 1) { outP = (__hip_bfloat16*)C0; bp = bA; }
  if constexpr (EPI == 5) {
    const bool isK = n0 >= 1024;
    outP = (__hip_bfloat16*)(isK ? C1 : C0);
    bp = isK ? bB : bA;
    ldO = 1024; colB = n0 & 1023;
  }
  if constexpr (EPI == 7) outP = (__hip_bfloat16*)C0 + (size_t)z * 4194304ull;
  if constexpr (EPI == 8)
    outP = (__hip_bfloat16*)C0 + ((z == 0) ? 0ull : ((z == 1) ? 4194304ull : 12582912ull));

#pragma unroll
  for (int nf = 0; nf < 4; ++nf) {
    int nn = wn + nf * 16 + row16;
    float bv = bp ? bp[colB + nn] : 0.f;
#pragma unroll
    for (int mf = 0; mf < 4; ++mf) {
      int mloc = wm + mf * 16 + grp * 4;
      f32x4 a = acc[mf][nf];
#pragma unroll
      for (int r = 0; r < 4; ++r) {
        float v = a[r] + bv;
        if constexpr (EPI == 1)
          v = 0.5f * v * (1.0f + erff(v * 0.70710678118654752f));
        *(short*)(smem + (mloc + r) * 272 + nn * 2) = f2bf(v);
      }
    }
  }
  __syncthreads();
#pragma unroll
  for (int i = 0; i < 8; ++i) {
    int c = t + i * 256;
    int mmr = c >> 4, nc = c & 15;
    u32x4 vv = *(const u32x4*)(smem + mmr * 272 + nc * 16);
    *(u32x4*)(outP + (size_t)(m0 + mmr) * ldO + colB + nc * 8) = vv;
  }
}

// ---------------- FF2 split-K reduce: out = h1 + b2 + sum(3 partials) --------
__global__ __launch_bounds__(256) void reduce3(const __hip_bfloat16* __restrict__ p0,
                                               const __hip_bfloat16* __restrict__ p1,
                                               const __hip_bfloat16* __restrict__ p2,
                                               const float* __restrict__ h1,
                                               const float* __restrict__ b2,
                                               float* __restrict__ out) {
  int idx = (blockIdx.x * 256 + threadIdx.x) * 8;
  int n = idx & 1023;
  bf16x8 a = *(const bf16x8*)(p0 + idx);
  bf16x8 b = *(const bf16x8*)(p1 + idx);
  bf16x8 c = *(const bf16x8*)(p2 + idx);
  float4 hA = *(const float4*)(h1 + idx), hB = *(const float4*)(h1 + idx + 4);
  float4 bA = *(const float4*)(b2 + n), bB = *(const float4*)(b2 + n + 4);
  float o[8];
#pragma unroll
  for (int j = 0; j < 8; ++j) {
    float fa = __builtin_bit_cast(float, ((unsigned)(unsigned short)a[j]) << 16);
    float fb = __builtin_bit_cast(float, ((unsigned)(unsigned short)b[j]) << 16);
    float fc = __builtin_bit_cast(float, ((unsigned)(unsigned short)c[j]) << 16);
    o[j] = fa + fb + fc;
  }
  float4 r0 = make_float4(o[0] + hA.x + bA.x, o[1] + hA.y + bA.y,
                          o[2] + hA.z + bA.z, o[3] + hA.w + bA.w);
  float4 r1 = make_float4(o[4] + hB.x + bB.x, o[5] + hB.y + bB.y,
                          o[6] + hB.z + bB.z, o[7] + hB.w + bB.w);
  *(float4*)(out + idx) = r0;
  *(float4*)(out + idx + 4) = r1;
}

// ---------------- O-proj split-K reduce: h1 = x + bo + sum(4 partials) -------
__global__ __launch_bounds__(256) void reduce4(const __hip_bfloat16* __restrict__ p0,
                                               const __hip_bfloat16* __restrict__ p1,
                                               const __hip_bfloat16* __restrict__ p2,
                                               const __hip_bfloat16* __restrict__ p3,
                                               const float* __restrict__ x,
                                               const float* __restrict__ bo,
                                               float* __restrict__ out) {
  int idx = (blockIdx.x * 256 + threadIdx.x) * 8;
  int n = idx & 1023;
  bf16x8 a = *(const bf16x8*)(p0 + idx);
  bf16x8 b = *(const bf16x8*)(p1 + idx);
  bf16x8 c = *(const bf16x8*)(p2 + idx);
  bf16x8 d = *(const bf16x8*)(p3 + idx);
  float4 hA = *(const float4*)(x + idx), hB = *(const float4*)(x + idx + 4);
  float4 bA = *(const float4*)(bo + n), bB = *(const float4*)(bo + n + 4);
  float o[8];
#pragma unroll
  for (int j = 0; j < 8; ++j) {
    float fa = __builtin_bit_cast(float, ((unsigned)(unsigned short)a[j]) << 16);
    float fb = __builtin_bit_cast(float, ((unsigned)(unsigned short)b[j]) << 16);
    float fc = __builtin_bit_cast(float, ((unsigned)(unsigned short)c[j]) << 16);
    float fd = __builtin_bit_cast(float, ((unsigned)(unsigned short)d[j]) << 16);
    o[j] = (fa + fb) + (fc + fd);
  }
  float4 r0 = make_float4(o[0] + hA.x + bA.x, o[1] + hA.y + bA.y,
                          o[2] + hA.z + bA.z, o[3] + hA.w + bA.w);
  float4 r1 = make_float4(o[4] + hB.x + bB.x, o[5] + hB.y + bB.y,
                          o[6] + hB.z + bB.z, o[7] + hB.w + bB.w);
  *(float4*)(out + idx) = r0;
  *(float4*)(out + idx + 4) = r1;
}

// ---------------- Flash attention v2 (verified) ------------------------------
__global__ __launch_bounds__(512) void flash_attn2(
    const __hip_bfloat16* __restrict__ Q,
    const __hip_bfloat16* __restrict__ Kg,
    const __hip_bfloat16* __restrict__ VTg,
    const float* __restrict__ mask,
    __hip_bfloat16* __restrict__ O) {
  __shared__ __align__(16) char lds[33280];
  const int t = threadIdx.x, lane = t & 63, w = t >> 6;
  const int l31 = lane & 31, hi = lane >> 5;
  const int q0 = blockIdx.x * 256;
  const int bh = blockIdx.y, b = bh >> 4, h = bh & 15;
  const int qrow = q0 + w * 32 + l31;

  bf16x8 qf[4];
  {
    const __hip_bfloat16* qp = Q + ((size_t)(b * SS + qrow)) * DD + h * HDIM + hi * 8;
    qf[0] = *(const bf16x8*)(qp);
    qf[1] = *(const bf16x8*)(qp + 16);
    qf[2] = *(const bf16x8*)(qp + 32);
    qf[3] = *(const bf16x8*)(qp + 48);
  }
  f32x16 ctx0 = {}, ctx1 = {};
  float m = -1e30f, l = 0.f, mC = -1.44e30f;

  auto stage = [&](int buf, int kv0) {
    int r = t >> 3, c = t & 7;
    gl_lds16(Kg + ((size_t)(b * SS + kv0 + r)) * DD + h * HDIM + ((c ^ (r & 7)) * 8),
             lds + buf * 8192 + t * 16);
    gl_lds16(VTg + ((size_t)(bh * 64 + r)) * 2048 + kv0 + ((c ^ (r & 7)) * 8),
             lds + 16384 + buf * 8192 + t * 16);
    if (t < 64) *(float*)(lds + 32768 + buf * 256 + t * 4) = mask[b * SS + kv0 + t];
  };

  stage(0, 0);
  for (int it = 0; it < SS / 64; ++it) {
    __syncthreads();
    if (it + 1 < SS / 64) stage((it + 1) & 1, (it + 1) * 64);
    const char* Kb = lds + (it & 1) * 8192;
    const char* Vb = lds + 16384 + (it & 1) * 8192;
    const float* mk = (const float*)(lds + 32768 + (it & 1) * 256);

    f32x16 s0 = {}, s1 = {};
#pragma unroll
    for (int kc = 0; kc < 4; ++kc) {
      int c = kc * 2 + hi;
      int r0 = l31, r1 = 32 + l31;
      bf16x8 ka0 = *(const bf16x8*)(Kb + r0 * 128 + ((c ^ (r0 & 7)) << 4));
      bf16x8 ka1 = *(const bf16x8*)(Kb + r1 * 128 + ((c ^ (r1 & 7)) << 4));
      s0 = __builtin_amdgcn_mfma_f32_32x32x16_bf16(ka0, qf[kc], s0, 0, 0, 0);
      s1 = __builtin_amdgcn_mfma_f32_32x32x16_bf16(ka1, qf[kc], s1, 0, 0, 0);
    }
#pragma unroll
    for (int g = 0; g < 4; ++g) {
      float4 mg0 = *(const float4*)(mk + g * 8 + hi * 4);
      float4 mg1 = *(const float4*)(mk + 32 + g * 8 + hi * 4);
      const float* m0p = (const float*)&mg0;
      const float* m1p = (const float*)&mg1;
#pragma unroll
      for (int i = 0; i < 4; ++i) {
        s0[g * 4 + i] = fmaf(s0[g * 4 + i], 0.125f, m0p[i]);
        s1[g * 4 + i] = fmaf(s1[g * 4 + i], 0.125f, m1p[i]);
      }
    }
    float pmax;
    {
      f32x16 q8;
#pragma unroll
      for (int r = 0; r < 16; ++r) q8[r] = fmaxf(s0[r], s1[r]);
#pragma unroll
      for (int r = 0; r < 8; ++r) q8[r] = fmaxf(q8[r], q8[r + 8]);
#pragma unroll
      for (int r = 0; r < 4; ++r) q8[r] = fmaxf(q8[r], q8[r + 4]);
      pmax = fmaxf(fmaxf(q8[0], q8[1]), fmaxf(q8[2], q8[3]));
      pmax = fmaxf(pmax, __shfl_xor(pmax, 32));
    }
    if (__any(pmax > m + 8.0f)) {
      float mnew = fmaxf(m, pmax);
      float fac = EXP2((m - mnew) * LOG2E);
      l *= fac;
#pragma unroll
      for (int r = 0; r < 16; ++r) { ctx0[r] *= fac; ctx1[r] *= fac; }
      m = mnew;
      mC = m * LOG2E;
    }
    float rsA = 0.f, rsB = 0.f;
#pragma unroll
    for (int r = 0; r < 16; ++r) {
      s0[r] = EXP2(fmaf(s0[r], LOG2E, -mC));
      s1[r] = EXP2(fmaf(s1[r], LOG2E, -mC));
      rsA += s0[r];
      rsB += s1[r];
    }
    rsA += rsB;
    rsA += __shfl_xor(rsA, 32);
    l += rsA;

    unsigned W0[8], W1[8];
#pragma unroll
    for (int g = 0; g < 4; ++g) {
      W0[g * 2] = pk2(s0[g * 4 + 0], s0[g * 4 + 1]);
      W0[g * 2 + 1] = pk2(s0[g * 4 + 2], s0[g * 4 + 3]);
      W1[g * 2] = pk2(s1[g * 4 + 0], s1[g * 4 + 1]);
      W1[g * 2 + 1] = pk2(s1[g * 4 + 2], s1[g * 4 + 3]);
    }
    unsigned swA0 = __shfl_xor(hi ? W0[0] : W0[2], 32);
    unsigned swA1 = __shfl_xor(hi ? W0[1] : W0[3], 32);
    unsigned swB0 = __shfl_xor(hi ? W0[4] : W0[6], 32);
    unsigned swB1 = __shfl_xor(hi ? W0[5] : W0[7], 32);
    unsigned swC0 = __shfl_xor(hi ? W1[0] : W1[2], 32);
    unsigned swC1 = __shfl_xor(hi ? W1[1] : W1[3], 32);
    unsigned swD0 = __shfl_xor(hi ? W1[4] : W1[6], 32);
    unsigned swD1 = __shfl_xor(hi ? W1[5] : W1[7], 32);
    u32x4 pb[4];
    pb[0] = hi ? (u32x4){swA0, swA1, W0[2], W0[3]} : (u32x4){W0[0], W0[1], swA0, swA1};
    pb[1] = hi ? (u32x4){swB0, swB1, W0[6], W0[7]} : (u32x4){W0[4], W0[5], swB0, swB1};
    pb[2] = hi ? (u32x4){swC0, swC1, W1[2], W1[3]} : (u32x4){W1[0], W1[1], swC0, swC1};
    pb[3] = hi ? (u32x4){swD0, swD1, W1[6], W1[7]} : (u32x4){W1[4], W1[5], swD0, swD1};

#pragma unroll
    for (int kc = 0; kc < 4; ++kc) {
      bf16x8 pbf = __builtin_bit_cast(bf16x8, pb[kc]);
      int c = kc * 2 + hi;
      int r0 = l31, r1 = 32 + l31;
      bf16x8 va0 = *(const bf16x8*)(Vb + r0 * 128 + ((c ^ (r0 & 7)) << 4));
      bf16x8 va1 = *(const bf16x8*)(Vb + r1 * 128 + ((c ^ (r1 & 7)) << 4));
      ctx0 = __builtin_amdgcn_mfma_f32_32x32x16_bf16(va0, pbf, ctx0, 0, 0, 0);
      ctx1 = __builtin_amdgcn_mfma_f32_32x32x16_bf16(va1, pbf, ctx1, 0, 0, 0);
    }
  }

  float inv = 1.0f / l;
#pragma unroll
  for (int r = 0; r < 16; ++r) { ctx0[r] *= inv; ctx1[r] *= inv; }
  __syncthreads();
  {
    int row = w * 32 + l31;
#pragma unroll
    for (int dt = 0; dt < 2; ++dt) {
#pragma unroll
      for (int g = 0; g < 4; ++g) {
        unsigned lo2 = dt ? pk2(ctx1[g * 4 + 0], ctx1[g * 4 + 1]) : pk2(ctx0[g * 4 + 0], ctx0[g * 4 + 1]);
        unsigned hi2 = dt ? pk2(ctx1[g * 4 + 2], ctx1[g * 4 + 3]) : pk2(ctx0[g * 4 + 2], ctx0[g * 4 + 3]);
        int c = dt * 4 + g;
        *(uint2*)(lds + row * 128 + ((c ^ (row & 7)) << 4) + hi * 8) = make_uint2(lo2, hi2);
      }
    }
  }
  __syncthreads();
  {
    int r = t >> 1;
    size_t tok = (size_t)(b * SS + q0 + r);
#pragma unroll
    for (int i = 0; i < 4; ++i) {
      int c = (t & 1) * 4 + i;
      u32x4 vv = *(const u32x4*)(lds + r * 128 + ((c ^ (r & 7)) << 4));
      *(u32x4*)((short*)O + tok * DD + h * HDIM + c * 8) = vv;
    }
  }
}

// ---------------- host-side orchestration ------------------------------------
extern "C" void kernel_launch(void* const* d_in, const int* in_sizes, int n_in,
                              void* d_out, int out_size, void* d_ws, size_t ws_size,
                              hipStream_t stream) {
  const float* x = (const float*)d_in[0];
  const float* mask = (const float*)d_in[1];
  const float* wq = (const float*)d_in[2];
  const float* bq = (const float*)d_in[3];
  const float* wk = (const float*)d_in[4];
  const float* bk = (const float*)d_in[5];
  const float* wv = (const float*)d_in[6];
  const float* bv = (const float*)d_in[7];
  const float* wo = (const float*)d_in[8];
  const float* bo = (const float*)d_in[9];
  const float* w1 = (const float*)d_in[10];
  const float* b1 = (const float*)d_in[11];
  const float* w2 = (const float*)d_in[12];
  const float* b2 = (const float*)d_in[13];
  const float* g1 = (const float*)d_in[14];
  const float* be1 = (const float*)d_in[15];
  const float* g2 = (const float*)d_in[16];
  const float* be2 = (const float*)d_in[17];

  char* ws = (char*)d_ws;
  const size_t MB = 1024ull * 1024ull;
  __hip_bfloat16* wqkvT = (__hip_bfloat16*)(ws + 0 * MB);   // [3072][1024], 6MB
  __hip_bfloat16* woT = (__hip_bfloat16*)(ws + 6 * MB);     // 2MB
  __hip_bfloat16* w1T = (__hip_bfloat16*)(ws + 8 * MB);     // 8MB
  __hip_bfloat16* w2T = (__hip_bfloat16*)(ws + 16 * MB);    // 8MB
  __hip_bfloat16* xn = (__hip_bfloat16*)(ws + 24 * MB);     // 8MB; later h2
  __hip_bfloat16* qb = (__hip_bfloat16*)(ws + 32 * MB);
  __hip_bfloat16* kb = (__hip_bfloat16*)(ws + 40 * MB);
  __hip_bfloat16* vtb = (__hip_bfloat16*)(ws + 48 * MB);    // V^T [32][64][2048]
  __hip_bfloat16* ctxb = (__hip_bfloat16*)(ws + 56 * MB);
  float* h1 = (float*)(ws + 64 * MB);                       // 16MB
  __hip_bfloat16* h2 = xn;
  __hip_bfloat16* a1 = qb;                                  // 32MB @ 32..64
  // O-proj bf16 partials: 24,32,40,48 MB (xn,qb,kb,vtb dead at that point)
  // FF2 bf16 partials: 0, 8, 24 MB (weights/h2 dead at that point)

  convT<<<dim3(32, 32), 256, 0, stream>>>(wq, wqkvT, 1024, 1024);
  convT<<<dim3(32, 32), 256, 0, stream>>>(wk, wqkvT + 1024 * 1024, 1024, 1024);
  convT<<<dim3(32, 32), 256, 0, stream>>>(wv, wqkvT + 2 * 1024 * 1024, 1024, 1024);
  convT<<<dim3(32, 32), 256, 0, stream>>>(wo, woT, 1024, 1024);
  convT<<<dim3(128, 32), 256, 0, stream>>>(w1, w1T, 1024, 4096);
  convT<<<dim3(32, 128), 256, 0, stream>>>(w2, w2T, 4096, 1024);

  ln_bf16<<<1024, 256, 0, stream>>>(x, g1, be1, xn);

  // fused QKV: M=4096, N=3072, K=1024 -> 768 blocks (3/CU)
  gemm_bt<5><<<dim3(24, 32), 256, 0, stream>>>(
      xn, wqkvT, bq, bk, bv, qb, kb, vtb, NTOK, 3072, 1024, 1);

  flash_attn2<<<dim3(8, 32), 512, 0, stream>>>(qb, kb, vtb, mask, ctxb);

  // O-proj split-K=4 -> bf16 partials @ 24+8z MB (1024 blocks)
  gemm_bt<7><<<dim3(8, 32, 4), 256, 0, stream>>>(
      ctxb, woT, nullptr, nullptr, nullptr, ws + 24 * MB, nullptr, nullptr,
      NTOK, 1024, 1024, 4);

  reduce4<<<2048, 256, 0, stream>>>((__hip_bfloat16*)(ws + 24 * MB),
                                    (__hip_bfloat16*)(ws + 32 * MB),
                                    (__hip_bfloat16*)(ws + 40 * MB),
                                    (__hip_bfloat16*)(ws + 48 * MB),
                                    x, bo, h1);

  ln_bf16<<<1024, 256, 0, stream>>>(h1, g2, be2, h2);

  // FF1 + gelu: M=4096, N=4096, K=1024 -> 1024 blocks (4/CU)
  gemm_bt<1><<<dim3(32, 32), 256, 0, stream>>>(
      h2, w1T, b1, nullptr, nullptr, a1, nullptr, nullptr, NTOK, FFD, 1024, 1);

  // FF2 split-K=3 -> bf16 partials @ 0/8/24 MB (768 blocks)
  gemm_bt<8><<<dim3(8, 32, 3), 256, 0, stream>>>(
      a1, w2T, nullptr, nullptr, nullptr, ws, nullptr, nullptr,
      NTOK, 1024, FFD, 3);

  reduce3<<<2048, 256, 0, stream>>>((__hip_bfloat16*)(ws + 0 * MB),
                                    (__hip_bfloat16*)(ws + 8 * MB),
                                    (__hip_bfloat16*)(ws + 24 * MB),
                                    h1, b2, (float*)d_out);
}